// Round 11
// baseline (477.071 us; speedup 1.0000x reference)
//
#include <hip/hip_runtime.h>
#include <hip/hip_bf16.h>

#define NQ 4096
#define NK 8192
#define NH 4
#define KSPLIT 16
#define KLEN (NK / KSPLIT)   // 512 keys per split
#define NQT64 (NQ / 64)      // 64 q-tiles of 64
#define NSUP 4               // split-groups surviving to combine
#define QSCALE (0.125f * 1.44269504088896340736f)  // 1/sqrt(64)*log2e

typedef __attribute__((ext_vector_type(8))) short bf16x8;
typedef __attribute__((ext_vector_type(4))) float f32x4;
typedef __attribute__((ext_vector_type(4))) _Float16 f16x4;

__device__ inline unsigned short f2bf(float f) {
  union { float f; unsigned u; } v; v.f = f;
  unsigned r = v.u + 0x7fff + ((v.u >> 16) & 1);  // RNE
  return (unsigned short)(r >> 16);
}

// ---------------------------------------------------------------------------
// 1. mask (int32 NQ x NK) -> TRANSPOSED bitmask bitsT[word32][row] (4 MB).
// ---------------------------------------------------------------------------
__global__ __launch_bounds__(256) void maskbits_kernel(
    const int* __restrict__ mask, unsigned* __restrict__ bitsT) {
  const int NW = 8192 * 4;                       // total waves
  int wid = blockIdx.x * 4 + (threadIdx.x >> 6);
  int lane = threadIdx.x & 63;
  for (int j = 0; j < 2; ++j) {
    int v[8];
#pragma unroll
    for (int u = 0; u < 8; ++u) {
      int c = wid + (j * 8 + u) * NW;   // u64 chunk id: row = c>>7, ch = c&127
      v[u] = mask[(size_t)(c >> 7) * NK + (c & 127) * 64 + lane];
    }
#pragma unroll
    for (int u = 0; u < 8; ++u) {
      unsigned long long b = __ballot(v[u] != 0);
      int c = wid + (j * 8 + u) * NW;
      int n = c >> 7, ch = c & 127;
      if (lane == 0)  bitsT[(size_t)(2 * ch) * NQ + n] = (unsigned)b;
      if (lane == 32) bitsT[(size_t)(2 * ch + 1) * NQ + n] = (unsigned)(b >> 32);
    }
  }
}

// ---------------------------------------------------------------------------
// 2. projections (unchanged): Q*QSCALE -> Qp bf16, K -> Kp bf16,
//    V -> Vf f16 fragment-linear (PV A-frag order).
// ---------------------------------------------------------------------------
__global__ __launch_bounds__(256) void proj_kernel(
    const float* __restrict__ xQ, const float* __restrict__ xK,
    const float* __restrict__ Wq, const float* __restrict__ Wk,
    const float* __restrict__ Wv,
    unsigned short* __restrict__ Qp, unsigned short* __restrict__ Kp,
    _Float16* __restrict__ Vf) {
  __shared__ __align__(16) unsigned short Wt[64][264];  // Wt[d][c], padded

  int b = blockIdx.x;
  int proj, h, rb;
  if (b < 64)        { proj = 0; h = b >> 4;  rb = b & 15; }
  else if (b < 192)  { proj = 1; b -= 64;  h = b >> 5; rb = b & 31; }
  else               { proj = 2; b -= 192; h = b >> 5; rb = b & 31; }
  const float* x = (proj == 0) ? xQ : xK;
  const float* W = (proj == 0 ? Wq : (proj == 1 ? Wk : Wv)) + (size_t)h * 256 * 64;

  for (int i = threadIdx.x; i < 16384; i += 256)
    Wt[i & 63][i >> 6] = f2bf(W[i]);
  __syncthreads();

  int lane = threadIdx.x & 63, wv = threadIdx.x >> 6;
  int quad = lane >> 4, n16 = lane & 15;
  int r0 = rb * 256 + wv * 64;

  f32x4 acc[4][4];
#pragma unroll
  for (int mt = 0; mt < 4; ++mt)
#pragma unroll
    for (int nt = 0; nt < 4; ++nt)
      acc[mt][nt] = (f32x4){0.f, 0.f, 0.f, 0.f};

#pragma unroll
  for (int it = 0; it < 8; ++it) {
    const int k0 = it * 32;
    bf16x8 af[4];
#pragma unroll
    for (int mt = 0; mt < 4; ++mt) {
      const float* xp = x + (size_t)(r0 + mt * 16 + n16) * 256 + k0 + quad * 8;
      const float4 a0 = *(const float4*)xp;
      const float4 a1 = *(const float4*)(xp + 4);
      bf16x8 a;
      a[0] = (short)f2bf(a0.x); a[1] = (short)f2bf(a0.y);
      a[2] = (short)f2bf(a0.z); a[3] = (short)f2bf(a0.w);
      a[4] = (short)f2bf(a1.x); a[5] = (short)f2bf(a1.y);
      a[6] = (short)f2bf(a1.z); a[7] = (short)f2bf(a1.w);
      af[mt] = a;
    }
    bf16x8 bfr[4];
#pragma unroll
    for (int nt = 0; nt < 4; ++nt)
      bfr[nt] = *(const bf16x8*)&Wt[nt * 16 + n16][k0 + quad * 8];
#pragma unroll
    for (int mt = 0; mt < 4; ++mt)
#pragma unroll
      for (int nt = 0; nt < 4; ++nt)
        acc[mt][nt] = __builtin_amdgcn_mfma_f32_16x16x32_bf16(
            af[mt], bfr[nt], acc[mt][nt], 0, 0, 0);
  }

  if (proj < 2) {
    unsigned short* outp =
        (proj == 0 ? Qp : Kp) + (size_t)h * (size_t)(proj == 0 ? NQ : NK) * 64;
    const float sc = (proj == 0) ? QSCALE : 1.0f;
#pragma unroll
    for (int mt = 0; mt < 4; ++mt)
#pragma unroll
      for (int nt = 0; nt < 4; ++nt)
#pragma unroll
        for (int r = 0; r < 4; ++r) {
          int row = r0 + mt * 16 + quad * 4 + r;
          int col = nt * 16 + n16;
          outp[(size_t)row * 64 + col] = f2bf(acc[mt][nt][r] * sc);
        }
  } else {
#pragma unroll
    for (int mt = 0; mt < 4; ++mt) {
      int tile = h * 256 + ((r0 + mt * 16) >> 5);
      int kr = mt & 1;
#pragma unroll
      for (int nt = 0; nt < 4; ++nt) {
        f16x4 pk;
        pk[0] = (_Float16)acc[mt][nt][0]; pk[1] = (_Float16)acc[mt][nt][1];
        pk[2] = (_Float16)acc[mt][nt][2]; pk[3] = (_Float16)acc[mt][nt][3];
        *(f16x4*)&Vf[(((size_t)tile * 8 + kr * 4 + nt) * 64 + lane) * 4] = pk;
      }
    }
  }
}

// ---------------------------------------------------------------------------
// 3. flash attention, 64 QUERIES PER WAVE (4 independent qc chains per iter
//    -> 2x ILP for latency hiding, half the K/V load traffic per query).
//    Q frags reloaded from L1 each iter (4 waves share one 8KB Q tile) to
//    keep arch-VGPR + 64 AGPR acc under the (256,4)=128 cap.
//    Block = 4 waves = 4 adjacent key-splits of one (h, qt64); in-block
//    LDS reduction -> Opart 8.4 MB (NSUP=4), cheap combine.
// ---------------------------------------------------------------------------
__global__ __launch_bounds__(256, 4) void attn_kernel(
    const unsigned short* __restrict__ Qp, const unsigned short* __restrict__ Kp,
    const _Float16* __restrict__ Vf, const unsigned* __restrict__ bitsT,
    _Float16* __restrict__ Opart, float* __restrict__ Lpart) {
  __shared__ __align__(16) float Ob[64][68];   // 17.4 KB, +4 pad
  __shared__ float Lb[64];

  int b = blockIdx.x;                 // 1024 = 4h x 64qt64 x 4ksg
  int ksg = b & 3, qt64 = (b >> 2) & 63, h = b >> 8;
  int wv = threadIdx.x >> 6, lane = threadIdx.x & 63;
  int quad = lane >> 4, n16 = lane & 15;
  int ks = ksg * 4 + wv;              // this wave's key-split
  int qb = qt64 * 64;

  f32x4 o[4][4];                      // [dt][qc], 64 AGPR
#pragma unroll
  for (int dt = 0; dt < 4; ++dt)
#pragma unroll
    for (int qc = 0; qc < 4; ++qc) o[dt][qc] = (f32x4){0.f, 0.f, 0.f, 0.f};
  float ls[4] = {0.f, 0.f, 0.f, 0.f};

  const unsigned short* Qbase = Qp + ((size_t)h * NQ + qb) * 64;
  const unsigned short* Kptr =
      Kp + (size_t)h * NK * 64 + (size_t)(ks * KLEN + n16) * 64 + quad * 8;
  const _Float16* Vbase = Vf + ((size_t)h * 256 + ks * 16) * 2048 + lane * 4;
  const unsigned* bT = bitsT + (size_t)(ks * 16) * NQ + qb;

#pragma unroll 2
  for (int kb = 0; kb < KLEN / 32; ++kb) {
    // K A-frags (bf16, K=32)
    const unsigned short* Kg = Kptr + (size_t)kb * 32 * 64;
    bf16x8 kf[2][2];
#pragma unroll
    for (int kr = 0; kr < 2; ++kr)
#pragma unroll
      for (int c = 0; c < 2; ++c)
        kf[kr][c] = *(const bf16x8*)(Kg + kr * 16 * 64 + c * 32);

    // V A-frags: fragment-linear, shared across all 4 qc
    const _Float16* Vg = Vbase + (size_t)kb * 2048;
    f16x4 vf[4][2];
#pragma unroll
    for (int kr = 0; kr < 2; ++kr)
#pragma unroll
      for (int dt = 0; dt < 4; ++dt)
        vf[dt][kr] = *(const f16x4*)(Vg + (kr * 4 + dt) * 256);

    // 4 independent query-chains
#pragma unroll
    for (int qc = 0; qc < 4; ++qc) {
      // Q frags from L1 (block-shared 8KB tile, same addrs every iter)
      bf16x8 q0 = *(const bf16x8*)&Qbase[(size_t)(qc * 16 + n16) * 64 + quad * 8];
      bf16x8 q1 = *(const bf16x8*)&Qbase[(size_t)(qc * 16 + n16) * 64 + 32 + quad * 8];
      unsigned wqa = bT[(size_t)kb * NQ + qc * 16 + n16];

      // S^T = K·Q^T
      f32x4 s[2];
#pragma unroll
      for (int kr = 0; kr < 2; ++kr) {
        f32x4 a2 = (f32x4){0.f, 0.f, 0.f, 0.f};
        a2 = __builtin_amdgcn_mfma_f32_16x16x32_bf16(kf[kr][0], q0, a2, 0, 0, 0);
        a2 = __builtin_amdgcn_mfma_f32_16x16x32_bf16(kf[kr][1], q1, a2, 0, 0, 0);
        s[kr] = a2;
      }

      // P = exp2(S^T) masked -> f16 B-frags (B-layout == C/D layout, K=16)
      unsigned wq = wqa >> (quad * 4);
      f16x4 pf[2];
#pragma unroll
      for (int kr = 0; kr < 2; ++kr) {
        float e0 = __builtin_amdgcn_exp2f(s[kr][0]);
        float e1 = __builtin_amdgcn_exp2f(s[kr][1]);
        float e2 = __builtin_amdgcn_exp2f(s[kr][2]);
        float e3 = __builtin_amdgcn_exp2f(s[kr][3]);
        e0 = (wq & (1u << (kr * 16 + 0))) ? e0 : 0.f;
        e1 = (wq & (1u << (kr * 16 + 1))) ? e1 : 0.f;
        e2 = (wq & (1u << (kr * 16 + 2))) ? e2 : 0.f;
        e3 = (wq & (1u << (kr * 16 + 3))) ? e3 : 0.f;
        ls[qc] += (e0 + e1) + (e2 + e3);
        f16x4 p;
        p[0] = (_Float16)e0; p[1] = (_Float16)e1;
        p[2] = (_Float16)e2; p[3] = (_Float16)e3;
        pf[kr] = p;
      }
#pragma unroll
      for (int dt = 0; dt < 4; ++dt) {
        o[dt][qc] = __builtin_amdgcn_mfma_f32_16x16x16f16(vf[dt][0], pf[0],
                                                          o[dt][qc], 0, 0, 0);
        o[dt][qc] = __builtin_amdgcn_mfma_f32_16x16x16f16(vf[dt][1], pf[1],
                                                          o[dt][qc], 0, 0, 0);
      }
    }
  }

  // l: reduce across quads
#pragma unroll
  for (int qc = 0; qc < 4; ++qc) {
    ls[qc] += __shfl_xor(ls[qc], 16);
    ls[qc] += __shfl_xor(ls[qc], 32);
  }

  // ---- in-block reduction over the 4 splits (sequential barriered phases)
#pragma unroll
  for (int w = 0; w < 4; ++w) {
    if (wv == w) {
      if (w == 0) {
#pragma unroll
        for (int qc = 0; qc < 4; ++qc) {
#pragma unroll
          for (int dt = 0; dt < 4; ++dt)
            *(f32x4*)&Ob[qc * 16 + n16][dt * 16 + quad * 4] = o[dt][qc];
          if (quad == 0) Lb[qc * 16 + n16] = ls[qc];
        }
      } else {
#pragma unroll
        for (int qc = 0; qc < 4; ++qc) {
#pragma unroll
          for (int dt = 0; dt < 4; ++dt) {
            f32x4 t = *(f32x4*)&Ob[qc * 16 + n16][dt * 16 + quad * 4];
            t += o[dt][qc];
            *(f32x4*)&Ob[qc * 16 + n16][dt * 16 + quad * 4] = t;
          }
          if (quad == 0) Lb[qc * 16 + n16] += ls[qc];
        }
      }
    }
    __syncthreads();
  }

  // cooperative coalesced store: tile = (h*NQT64 + qt64)*NSUP + ksg
  const size_t tile = ((size_t)h * NQT64 + qt64) * NSUP + ksg;
  {
    int tid = threadIdx.x;
    int r = tid >> 2, c0 = (tid & 3) * 16;   // 64 rows x 64 cols, 16/thread
#pragma unroll
    for (int g = 0; g < 4; ++g) {
      f32x4 a = *(f32x4*)&Ob[r][c0 + g * 4];
      f16x4 ov;
      ov[0] = (_Float16)a[0]; ov[1] = (_Float16)a[1];
      ov[2] = (_Float16)a[2]; ov[3] = (_Float16)a[3];
      *(f16x4*)&Opart[(tile * 64 + r) * 64 + c0 + g * 4] = ov;
    }
    if (tid < 64) Lpart[tile * 64 + tid] = Lb[tid];
  }
}

// ---------------------------------------------------------------------------
// 4. combine NSUP partials + fused gates + @Wo + bo. 256 blocks x 16 rows
// ---------------------------------------------------------------------------
__global__ __launch_bounds__(256) void combine_kernel(
    const _Float16* __restrict__ Opart, const float* __restrict__ Lpart,
    const float* __restrict__ xQ, const float* __restrict__ Wg,
    const float* __restrict__ bg, const float* __restrict__ Wo,
    const float* __restrict__ bo, float* __restrict__ out) {
  __shared__ float comb[16][64];
  __shared__ float gred[16][4][4];
  __shared__ float glds[16][4];
  int nb = blockIdx.x;
  int tid = threadIdx.x;

  // gates for this block's 16 rows
  {
    int r = tid >> 4, hh = (tid >> 2) & 3, c = tid & 3;
    const float* xp = xQ + (size_t)(nb * 16 + r) * 256 + c * 64;
    const float* wp = Wg + hh * 256 + c * 64;
    float s = 0.f;
#pragma unroll
    for (int e = 0; e < 64; ++e) s = fmaf(xp[e], wp[e], s);
    gred[r][hh][c] = s;
  }
  __syncthreads();
  if (tid < 64) {
    int r = tid >> 2, hh = tid & 3;
    float s = gred[r][hh][0] + gred[r][hh][1] + gred[r][hh][2] + gred[r][hh][3];
    glds[r][hh] = 1.f / (1.f + __expf(-(s + bg[hh])));
  }
  __syncthreads();

  int r4 = tid >> 6, a = tid & 63;

  for (int p = 0; p < 4; ++p) {
    int r = p * 4 + r4;
    int n = nb * 16 + r;
    int qt64 = n >> 6, rl = n & 63;
    float csum = 0.f;
#pragma unroll
    for (int h = 0; h < NH; ++h) {
      size_t t0 = ((size_t)h * NQT64 + qt64) * NSUP;
      float accO = 0.f, lt = 0.f;
#pragma unroll
      for (int s = 0; s < NSUP; ++s) {
        size_t t = t0 + s;
        accO += (float)Opart[(t * 64 + rl) * 64 + a];
        lt += Lpart[t * 64 + rl];
      }
      csum += glds[r][h] * accO / lt;
    }
    comb[r][a] = csum;
  }
  __syncthreads();

  int j = tid;
  float accv[16];
#pragma unroll
  for (int r = 0; r < 16; ++r) accv[r] = bo[j];
  for (int aa = 0; aa < 64; ++aa) {
    float w = Wo[(size_t)aa * 256 + j];
#pragma unroll
    for (int r = 0; r < 16; ++r) accv[r] = fmaf(comb[r][aa], w, accv[r]);
  }
#pragma unroll
  for (int r = 0; r < 16; ++r)
    out[(size_t)(nb * 16 + r) * 256 + j] = accv[r];
}

// ---------------------------------------------------------------------------
extern "C" void kernel_launch(void* const* d_in, const int* in_sizes, int n_in,
                              void* d_out, int out_size, void* d_ws, size_t ws_size,
                              hipStream_t stream) {
  const float* xQ  = (const float*)d_in[0];
  const float* xK  = (const float*)d_in[1];
  const int*   mask= (const int*)d_in[2];
  const float* Wq  = (const float*)d_in[3];
  const float* Wk  = (const float*)d_in[4];
  const float* Wv  = (const float*)d_in[5];
  const float* Wg  = (const float*)d_in[6];
  const float* bg  = (const float*)d_in[7];
  const float* Wo  = (const float*)d_in[8];
  const float* bo  = (const float*)d_in[9];
  float* out = (float*)d_out;

  char* ws = (char*)d_ws;
  unsigned short* Qp   = (unsigned short*)(ws + 0);         // 2 MB
  unsigned short* Kp   = (unsigned short*)(ws + 2097152);   // 4 MB
  _Float16*       Vfp  = (_Float16*)(ws + 6291456);         // 4 MB frag-linear
  unsigned*       bitsT= (unsigned*)(ws + 10485760);        // 4 MB [word][row]
  float*          Lp   = (float*)(ws + 14680064);           // 256 KB
  _Float16*       Op   = (_Float16*)(ws + 15728640);        // 8.4 MB f16

  maskbits_kernel<<<dim3(8192), dim3(256), 0, stream>>>(mask, bitsT);
  proj_kernel<<<dim3(320), dim3(256), 0, stream>>>(xQ, xK, Wq, Wk, Wv, Qp, Kp, Vfp);
  attn_kernel<<<dim3(1024), dim3(256), 0, stream>>>(Qp, Kp, Vfp, bitsT, Op, Lp);
  combine_kernel<<<dim3(NQ / 16), dim3(256), 0, stream>>>(Op, Lp, xQ, Wg, bg,
                                                          Wo, bo, out);
}